// Round 1
// baseline (352.462 us; speedup 1.0000x reference)
//
#include <hip/hip_runtime.h>

static constexpr int TT = 100, BB = 256, DD = 784, HH = 256;
static constexpr float THRv = 1.0f, BETAv = 0.9f;

// TN GEMM: C[M,N] = A[M,K] @ B[N,K]^T + bias[N]
// A, B row-major with K contiguous. M % 128 == 0, K % BK == 0. N guarded.
template<int BK>
__global__ __launch_bounds__(256)
void gemm_tn_128(const float* __restrict__ A, const float* __restrict__ Bmat,
                 const float* __restrict__ bias, float* __restrict__ C,
                 int M, int N, int K) {
  constexpr int BM = 128, BN = 128;
  __shared__ float As[BK][BM + 4];
  __shared__ float Bs[BK][BN + 4];
  const int tid = threadIdx.x;
  const int tx = tid & 15;   // n-direction thread coord (16)
  const int ty = tid >> 4;   // m-direction thread coord (16)
  const int bm = blockIdx.x * BM;
  const int bn = blockIdx.y * BN;

  float acc[8][8];
#pragma unroll
  for (int i = 0; i < 8; ++i)
#pragma unroll
    for (int j = 0; j < 8; ++j) acc[i][j] = 0.0f;

  // staging: each thread loads one float4 from two rows (r0 and r0+64)
  const int q  = (tid & 3) * 4;  // k offset within tile (BK=16 -> 4 quads)
  const int r0 = tid >> 2;       // row 0..63

  const int nk = K / BK;
  for (int kb = 0; kb < nk; ++kb) {
    const int kg = kb * BK + q;
    const float4 av0 = *reinterpret_cast<const float4*>(&A[(size_t)(bm + r0) * K + kg]);
    const float4 av1 = *reinterpret_cast<const float4*>(&A[(size_t)(bm + r0 + 64) * K + kg]);
    float4 bv0 = make_float4(0.f, 0.f, 0.f, 0.f);
    float4 bv1 = make_float4(0.f, 0.f, 0.f, 0.f);
    if (bn + r0 < N)
      bv0 = *reinterpret_cast<const float4*>(&Bmat[(size_t)(bn + r0) * K + kg]);
    if (bn + r0 + 64 < N)
      bv1 = *reinterpret_cast<const float4*>(&Bmat[(size_t)(bn + r0 + 64) * K + kg]);
    __syncthreads();
    As[q + 0][r0]      = av0.x; As[q + 1][r0]      = av0.y;
    As[q + 2][r0]      = av0.z; As[q + 3][r0]      = av0.w;
    As[q + 0][r0 + 64] = av1.x; As[q + 1][r0 + 64] = av1.y;
    As[q + 2][r0 + 64] = av1.z; As[q + 3][r0 + 64] = av1.w;
    Bs[q + 0][r0]      = bv0.x; Bs[q + 1][r0]      = bv0.y;
    Bs[q + 2][r0]      = bv0.z; Bs[q + 3][r0]      = bv0.w;
    Bs[q + 0][r0 + 64] = bv1.x; Bs[q + 1][r0 + 64] = bv1.y;
    Bs[q + 2][r0 + 64] = bv1.z; Bs[q + 3][r0 + 64] = bv1.w;
    __syncthreads();
#pragma unroll
    for (int k = 0; k < BK; ++k) {
      const float4 a0 = *reinterpret_cast<const float4*>(&As[k][ty * 4]);
      const float4 a1 = *reinterpret_cast<const float4*>(&As[k][ty * 4 + 64]);
      const float4 b0 = *reinterpret_cast<const float4*>(&Bs[k][tx * 4]);
      const float4 b1 = *reinterpret_cast<const float4*>(&Bs[k][tx * 4 + 64]);
      const float am[8] = {a0.x, a0.y, a0.z, a0.w, a1.x, a1.y, a1.z, a1.w};
      const float bb[8] = {b0.x, b0.y, b0.z, b0.w, b1.x, b1.y, b1.z, b1.w};
#pragma unroll
      for (int i = 0; i < 8; ++i)
#pragma unroll
        for (int j = 0; j < 8; ++j)
          acc[i][j] = __fmaf_rn(am[i], bb[j], acc[i][j]);
    }
  }

#pragma unroll
  for (int i = 0; i < 8; ++i) {
    const int row = bm + ty * 4 + (i & 3) + ((i >> 2) * 64);
    if (row >= M) continue;
#pragma unroll
    for (int jh = 0; jh < 2; ++jh) {
      const int col = bn + tx * 4 + jh * 64;
      if (col >= N) continue;
      const float4 bv = *reinterpret_cast<const float4*>(&bias[col]);
      float4 o;
      o.x = acc[i][jh * 4 + 0] + bv.x;
      o.y = acc[i][jh * 4 + 1] + bv.y;
      o.z = acc[i][jh * 4 + 2] + bv.z;
      o.w = acc[i][jh * 4 + 3] + bv.w;
      *reinterpret_cast<float4*>(&C[(size_t)row * N + col]) = o;
    }
  }
}

// LIF scan over T: mem = beta*mem + cur - (mem_prev > thr); spk = (mem > thr).
// cur and spk may alias (in-place). NE % 256 == 0.
__global__ __launch_bounds__(256)
void lif_scan(const float* __restrict__ cur, float* __restrict__ spk,
              int NE, int nt) {
  const int tid = blockIdx.x * 256 + threadIdx.x;
  float mem = 0.0f;
  for (int t = 0; t < nt; ++t) {
    const float c = cur[(size_t)t * NE + tid];
    const float reset = (mem > THRv) ? THRv : 0.0f;
    // match numpy op-by-op: (beta*mem) + cur, then - reset  (no FMA fusion)
    mem = __fsub_rn(__fadd_rn(__fmul_rn(BETAv, mem), c), reset);
    spk[(size_t)t * NE + tid] = (mem > THRv) ? 1.0f : 0.0f;
  }
}

extern "C" void kernel_launch(void* const* d_in, const int* in_sizes, int n_in,
                              void* d_out, int out_size, void* d_ws, size_t ws_size,
                              hipStream_t stream) {
  const float* x  = (const float*)d_in[0];  // [T,B,D] binary spikes
  const float* W1 = (const float*)d_in[1];  // [H,D]
  const float* b1 = (const float*)d_in[2];  // [H]
  const float* W2 = (const float*)d_in[3];  // [D,H]
  const float* b2 = (const float*)d_in[4];  // [D]
  float* out = (float*)d_out;               // [T,B,D]

  float* cur1 = (float*)d_ws;                       // T*B*H floats = 26.2 MB
  float* spk1 = cur1 + (size_t)TT * BB * HH;        // T*B*H floats = 26.2 MB

  const int M = TT * BB;  // 25600
  dim3 blk(256);

  // layer 1 currents: cur1 = X @ W1^T + b1   [M, H], K = D = 784 (49*16)
  gemm_tn_128<16><<<dim3(M / 128, (HH + 127) / 128), blk, 0, stream>>>(
      x, W1, b1, cur1, M, HH, DD);
  // layer 1 LIF recurrence -> spk1
  lif_scan<<<dim3((BB * HH) / 256), blk, 0, stream>>>(cur1, spk1, BB * HH, TT);
  // layer 2 currents into d_out: cur2 = spk1 @ W2^T + b2   [M, D], K = H = 256
  gemm_tn_128<16><<<dim3(M / 128, (DD + 127) / 128), blk, 0, stream>>>(
      spk1, W2, b2, out, M, DD, HH);
  // layer 2 LIF recurrence, in place on d_out
  lif_scan<<<dim3((BB * DD) / 256), blk, 0, stream>>>(out, out, BB * DD, TT);
}

// Round 2
// 171.027 us; speedup vs baseline: 2.0609x; 2.0609x over previous
//
#include <hip/hip_runtime.h>

typedef __attribute__((ext_vector_type(8))) short bf16x8;
typedef __attribute__((ext_vector_type(4))) float f32x4;

static constexpr int TT = 100, BB = 256, DD = 784, HH = 256;
static constexpr int MM = TT * BB;      // 25600
static constexpr int K1PAD = 800;       // 784 padded to 25*32

__device__ __forceinline__ unsigned short f2bf(float x) {
  unsigned u = __float_as_uint(x);
  unsigned r = (u + 0x7FFFu + ((u >> 16) & 1u)) >> 16;
  return (unsigned short)r;
}
__device__ __forceinline__ float bf2f(unsigned short h) {
  return __uint_as_float(((unsigned)h) << 16);
}

// Split fp32 weights into 3 exact-ish bf16 planes (w = hi+mid+lo, err <= 2^-27 |w|),
// zero-padding K to Kpad.
__global__ __launch_bounds__(256)
void split_w(const float* __restrict__ W, unsigned short* __restrict__ Ws,
             int N, int K, int Kpad) {
  int idx = blockIdx.x * 256 + threadIdx.x;
  int total = N * Kpad;
  if (idx >= total) return;
  int row = idx / Kpad, col = idx - row * Kpad;
  float w = (col < K) ? W[row * K + col] : 0.0f;
  unsigned short h0 = f2bf(w);
  float r1 = w - bf2f(h0);          // exact
  unsigned short h1 = f2bf(r1);
  float r2 = r1 - bf2f(h1);         // exact
  unsigned short h2 = f2bf(r2);
  Ws[idx] = h0;
  Ws[total + idx] = h1;
  Ws[2 * total + idx] = h2;
}

// C[M,N] = A[M,K] @ (sum of 3 bf16 planes of B[N,K])^T + bias[N]
// A: fp32 (CONV_A, converted in staging) or bf16 (row stride Kpad==K).
// BM=BN=128, BK=32, 4 waves (2x2), mfma_f32_16x16x32_bf16, acc 4x4 frags.
template<bool CONV_A, bool GUARD_K, bool GUARD_N>
__global__ __launch_bounds__(256)
void gemm_mfma(const void* __restrict__ Aptr, const unsigned short* __restrict__ Bs,
               size_t planeStride, const float* __restrict__ bias,
               float* __restrict__ C, int M, int N, int K, int Kpad) {
  __shared__ unsigned short Asm[128][40];     // 32 cols + 8 pad (80B row stride)
  __shared__ unsigned short Bsm[3][128][40];
  const int tid = threadIdx.x;
  const int bm = blockIdx.x * 128;
  const int bn = blockIdx.y * 128;
  const int wid = tid >> 6;
  const int lane = tid & 63;
  const int wr = (wid >> 1) * 64;
  const int wc = (wid & 1) * 64;
  const int l15 = lane & 15;
  const int l4 = lane >> 4;

  f32x4 acc[4][4];
#pragma unroll
  for (int m = 0; m < 4; ++m)
#pragma unroll
    for (int n = 0; n < 4; ++n) acc[m][n] = (f32x4){0.f, 0.f, 0.f, 0.f};

  // staging map: octet o (8 elems) -> row = o>>2, col-octet = (o&3)*8; thread owns o=tid, tid+256
  const int r0 = tid >> 2;
  const int c0 = (tid & 3) * 8;

  const int nkb = Kpad / 32;
  for (int kb = 0; kb < nkb; ++kb) {
    const int k0 = kb * 32;
    uint4 a_st[2];
    if (CONV_A) {
      const float* A = (const float*)Aptr;
#pragma unroll
      for (int i = 0; i < 2; ++i) {
        const int row = r0 + i * 64;
        const int col = k0 + c0;
        float4 f0 = make_float4(0.f, 0.f, 0.f, 0.f), f1 = f0;
        if (!GUARD_K || col < K) {   // 784 % 8 == 0: whole octet in/out
          f0 = *(const float4*)&A[(size_t)(bm + row) * K + col];
          f1 = *(const float4*)&A[(size_t)(bm + row) * K + col + 4];
        }
        uint4 v;
        v.x = (unsigned)f2bf(f0.x) | ((unsigned)f2bf(f0.y) << 16);
        v.y = (unsigned)f2bf(f0.z) | ((unsigned)f2bf(f0.w) << 16);
        v.z = (unsigned)f2bf(f1.x) | ((unsigned)f2bf(f1.y) << 16);
        v.w = (unsigned)f2bf(f1.z) | ((unsigned)f2bf(f1.w) << 16);
        a_st[i] = v;
      }
    } else {
      const unsigned short* A = (const unsigned short*)Aptr;
#pragma unroll
      for (int i = 0; i < 2; ++i) {
        const int row = r0 + i * 64;
        a_st[i] = *(const uint4*)&A[(size_t)(bm + row) * Kpad + k0 + c0];
      }
    }
    uint4 b_st[3][2];
#pragma unroll
    for (int s = 0; s < 3; ++s)
#pragma unroll
      for (int i = 0; i < 2; ++i) {
        const int row = r0 + i * 64;
        uint4 v = {0u, 0u, 0u, 0u};
        if (!GUARD_N || bn + row < N)
          v = *(const uint4*)&Bs[(size_t)s * planeStride + (size_t)(bn + row) * Kpad + k0 + c0];
        b_st[s][i] = v;
      }

    __syncthreads();
#pragma unroll
    for (int i = 0; i < 2; ++i)
      *(uint4*)&Asm[r0 + i * 64][c0] = a_st[i];
#pragma unroll
    for (int s = 0; s < 3; ++s)
#pragma unroll
      for (int i = 0; i < 2; ++i)
        *(uint4*)&Bsm[s][r0 + i * 64][c0] = b_st[s][i];
    __syncthreads();

    bf16x8 afr[4];
#pragma unroll
    for (int m = 0; m < 4; ++m)
      afr[m] = *(const bf16x8*)&Asm[wr + m * 16 + l15][l4 * 8];
#pragma unroll
    for (int s = 0; s < 3; ++s) {
      bf16x8 bfr[4];
#pragma unroll
      for (int n = 0; n < 4; ++n)
        bfr[n] = *(const bf16x8*)&Bsm[s][wc + n * 16 + l15][l4 * 8];
#pragma unroll
      for (int m = 0; m < 4; ++m)
#pragma unroll
        for (int n = 0; n < 4; ++n)
          acc[m][n] = __builtin_amdgcn_mfma_f32_16x16x32_bf16(afr[m], bfr[n], acc[m][n], 0, 0, 0);
    }
  }

#pragma unroll
  for (int m = 0; m < 4; ++m)
#pragma unroll
    for (int n = 0; n < 4; ++n) {
      const int col = bn + wc + n * 16 + l15;
      if (GUARD_N && col >= N) continue;
      const float bv = bias[col];
#pragma unroll
      for (int r = 0; r < 4; ++r) {
        const int row = bm + wr + m * 16 + l4 * 4 + r;
        C[(size_t)row * N + col] = acc[m][n][r] + bv;
      }
    }
}

// LIF scan, fp32 currents -> bf16 spikes (exact 0/1)
__global__ __launch_bounds__(256)
void lif_scan_bf(const float* __restrict__ cur, unsigned short* __restrict__ spk,
                 int NE, int nt) {
  const int tid = blockIdx.x * 256 + threadIdx.x;
  float mem = 0.0f;
  for (int t = 0; t < nt; ++t) {
    const float c = cur[(size_t)t * NE + tid];
    const float reset = (mem > 1.0f) ? 1.0f : 0.0f;
    mem = __fsub_rn(__fadd_rn(__fmul_rn(0.9f, mem), c), reset);
    spk[(size_t)t * NE + tid] = (mem > 1.0f) ? (unsigned short)0x3F80 : (unsigned short)0;
  }
}

// LIF scan, fp32 in-place (cur and spk alias)
__global__ __launch_bounds__(256)
void lif_scan_f32(const float* cur, float* spk, int NE, int nt) {
  const int tid = blockIdx.x * 256 + threadIdx.x;
  float mem = 0.0f;
  for (int t = 0; t < nt; ++t) {
    const float c = cur[(size_t)t * NE + tid];
    const float reset = (mem > 1.0f) ? 1.0f : 0.0f;
    mem = __fsub_rn(__fadd_rn(__fmul_rn(0.9f, mem), c), reset);
    spk[(size_t)t * NE + tid] = (mem > 1.0f) ? 1.0f : 0.0f;
  }
}

extern "C" void kernel_launch(void* const* d_in, const int* in_sizes, int n_in,
                              void* d_out, int out_size, void* d_ws, size_t ws_size,
                              hipStream_t stream) {
  const float* x  = (const float*)d_in[0];  // [T,B,D]
  const float* W1 = (const float*)d_in[1];  // [H,D]
  const float* b1 = (const float*)d_in[2];  // [H]
  const float* W2 = (const float*)d_in[3];  // [D,H]
  const float* b2 = (const float*)d_in[4];  // [D]
  float* out = (float*)d_out;               // [T,B,D]

  const size_t w1s_elems = (size_t)3 * HH * K1PAD;   // 614400
  const size_t w2s_elems = (size_t)3 * DD * HH;      // 602112
  unsigned short* W1s = (unsigned short*)d_ws;
  unsigned short* W2s = W1s + w1s_elems;
  float* cur1 = (float*)(W2s + w2s_elems);
  unsigned short* spk1 = (unsigned short*)(cur1 + (size_t)MM * HH);

  dim3 blk(256);

  // weight splits (zero-padded K for W1)
  split_w<<<dim3((HH * K1PAD + 255) / 256), blk, 0, stream>>>(W1, W1s, HH, DD, K1PAD);
  split_w<<<dim3((DD * HH + 255) / 256), blk, 0, stream>>>(W2, W2s, DD, HH, HH);

  // layer 1: cur1[M,256] = X[M,784] @ W1^T + b1   (A converted fp32->bf16 in staging)
  gemm_mfma<true, true, false><<<dim3(MM / 128, HH / 128), blk, 0, stream>>>(
      x, W1s, (size_t)HH * K1PAD, b1, cur1, MM, HH, DD, K1PAD);

  // layer 1 LIF -> bf16 spikes
  lif_scan_bf<<<dim3((BB * HH) / 256), blk, 0, stream>>>(cur1, spk1, BB * HH, TT);

  // layer 2: out[M,784] = spk1[M,256] @ W2^T + b2
  gemm_mfma<false, false, true><<<dim3(MM / 128, (DD + 127) / 128), blk, 0, stream>>>(
      spk1, W2s, (size_t)DD * HH, b2, out, MM, DD, HH, HH);

  // layer 2 LIF in place on d_out
  lif_scan_f32<<<dim3((BB * DD) / 256), blk, 0, stream>>>(out, out, BB * DD, TT);
}

// Round 3
// 161.537 us; speedup vs baseline: 2.1819x; 1.0587x over previous
//
#include <hip/hip_runtime.h>

typedef __attribute__((ext_vector_type(8))) short bf16x8;
typedef __attribute__((ext_vector_type(4))) float f32x4;

static constexpr int TT = 100, BB = 256, DD = 784, HH = 256;
static constexpr int MM = TT * BB;      // 25600
static constexpr int K1PAD = 800;       // 784 -> 25*32
static constexpr int N2PAD = 896;       // 784 -> 7*128

__device__ __forceinline__ unsigned short f2bf(float x) {
  unsigned u = __float_as_uint(x);
  return (unsigned short)((u + 0x7FFFu + ((u >> 16) & 1u)) >> 16);
}
__device__ __forceinline__ float bf2f(unsigned short h) {
  return __uint_as_float(((unsigned)h) << 16);
}

__device__ __forceinline__ void glds16(const void* g, void* l) {
  __builtin_amdgcn_global_load_lds(
      (const __attribute__((address_space(1))) unsigned int*)g,
      (__attribute__((address_space(3))) unsigned int*)l, 16, 0, 0);
}

// Split fp32 W[N][K] into 3 bf16 planes [Npad][Kpad] (w = p0+p1+p2, err <= 2^-27|w|),
// zero padding rows >= N and cols >= K.
__global__ __launch_bounds__(256)
void split_w(const float* __restrict__ W, unsigned short* __restrict__ Ws,
             int N, int K, int Npad, int Kpad) {
  int idx = blockIdx.x * 256 + threadIdx.x;
  int total = Npad * Kpad;
  if (idx >= total) return;
  int row = idx / Kpad, col = idx - row * Kpad;
  float w = (row < N && col < K) ? W[row * K + col] : 0.0f;
  unsigned short h0 = f2bf(w);
  float r1 = w - bf2f(h0);
  unsigned short h1 = f2bf(r1);
  float r2 = r1 - bf2f(h1);
  unsigned short h2 = f2bf(r2);
  Ws[idx] = h0;
  Ws[total + idx] = h1;
  Ws[2 * total + idx] = h2;
}

// C[M,N] = A[M,K] @ (sum of 3 bf16 planes of B)^T + bias[N]
// BM=BN=128, BK=32, 4 waves 2x2 (64x64 each), mfma_f32_16x16x32_bf16.
// LDS linear [128][32] per tile (64-B rows): glds dest = base + lane*16 maps to
// (row=lane>>2, chunk=lane&3) == row-major source order -> conflict-free, no pad.
// CONV_A: A is fp32, reg-staged with fp32->bf16 convert (prefetched 1 kb ahead);
// else A is bf16 with row stride Kpad, loaded via glds.
template<bool CONV_A, bool GUARD_KA, bool GUARD_NST>
__global__ __launch_bounds__(256)
void gemm_mfma(const void* __restrict__ Aptr, const unsigned short* __restrict__ Bs,
               size_t planeStride, const float* __restrict__ bias,
               float* __restrict__ C, int M, int N, int K, int Kpad) {
  __shared__ unsigned short Asm[128][32];       // 8 KB
  __shared__ unsigned short Bsm[3][128][32];    // 24 KB
  const int tid = threadIdx.x;
  const int bm = blockIdx.x * 128, bn = blockIdx.y * 128;
  const int wid = tid >> 6, lane = tid & 63;
  const int wr = (wid >> 1) * 64, wc = (wid & 1) * 64;
  const int l15 = lane & 15, l4 = lane >> 4;

  f32x4 acc[4][4];
#pragma unroll
  for (int m = 0; m < 4; ++m)
#pragma unroll
    for (int n = 0; n < 4; ++n) acc[m][n] = (f32x4){0.f, 0.f, 0.f, 0.f};

  // glds geometry: wave wid covers tile rows [wid*32, wid*32+32), two 16-row issues.
  const int rl = wid * 32 + (lane >> 2);   // issue-0 row (lane-dependent)
  const int ce = (lane & 3) * 8;           // element offset of this lane's chunk

  const unsigned short* bsrc[3][2];
#pragma unroll
  for (int s = 0; s < 3; ++s)
#pragma unroll
    for (int i = 0; i < 2; ++i)
      bsrc[s][i] = Bs + (size_t)s * planeStride + (size_t)(bn + rl + i * 16) * Kpad + ce;

  const unsigned short* asrc[2];
  if (!CONV_A) {
    const unsigned short* Ab = (const unsigned short*)Aptr;
#pragma unroll
    for (int i = 0; i < 2; ++i)
      asrc[i] = Ab + (size_t)(bm + rl + i * 16) * Kpad + ce;
  }

  // CONV_A staging map: thread -> (row = tid>>2 [+64], chunk = tid&3)
  const int r0 = tid >> 2, c0 = (tid & 3) * 8;
  const float* Af = (const float*)Aptr;
  uint4 a_st[2];

  auto loadA = [&](int kb) {
    const int col = kb * 32 + c0;
#pragma unroll
    for (int i = 0; i < 2; ++i) {
      const int row = bm + r0 + i * 64;
      float4 f0 = make_float4(0.f, 0.f, 0.f, 0.f), f1 = f0;
      if (!GUARD_KA || col < K) {     // K % 8 == 0: whole octet in/out
        f0 = *(const float4*)&Af[(size_t)row * K + col];
        f1 = *(const float4*)&Af[(size_t)row * K + col + 4];
      }
      uint4 v;
      v.x = (unsigned)f2bf(f0.x) | ((unsigned)f2bf(f0.y) << 16);
      v.y = (unsigned)f2bf(f0.z) | ((unsigned)f2bf(f0.w) << 16);
      v.z = (unsigned)f2bf(f1.x) | ((unsigned)f2bf(f1.y) << 16);
      v.w = (unsigned)f2bf(f1.z) | ((unsigned)f2bf(f1.w) << 16);
      a_st[i] = v;
    }
  };

  if (CONV_A) loadA(0);

  const int nkb = Kpad / 32;
  for (int kb = 0; kb < nkb; ++kb) {
    const int k0 = kb * 32;
    __syncthreads();                      // previous compute done; LDS reusable
    if (CONV_A) {
      *(uint4*)&Asm[r0][c0]      = a_st[0];
      *(uint4*)&Asm[r0 + 64][c0] = a_st[1];
    } else {
      glds16(asrc[0] + k0, &Asm[wid * 32][0]);
      glds16(asrc[1] + k0, &Asm[wid * 32 + 16][0]);
    }
#pragma unroll
    for (int s = 0; s < 3; ++s) {
      glds16(bsrc[s][0] + k0, &Bsm[s][wid * 32][0]);
      glds16(bsrc[s][1] + k0, &Bsm[s][wid * 32 + 16][0]);
    }
    if (CONV_A && kb + 1 < nkb) loadA(kb + 1);   // prefetch next A into regs
    __syncthreads();                      // drains vmcnt (glds) + lgkm (ds_write)

    bf16x8 afr[4];
#pragma unroll
    for (int m = 0; m < 4; ++m)
      afr[m] = *(const bf16x8*)&Asm[wr + m * 16 + l15][l4 * 8];
#pragma unroll
    for (int s = 0; s < 3; ++s) {
      bf16x8 bfr[4];
#pragma unroll
      for (int n = 0; n < 4; ++n)
        bfr[n] = *(const bf16x8*)&Bsm[s][wc + n * 16 + l15][l4 * 8];
#pragma unroll
      for (int m = 0; m < 4; ++m)
#pragma unroll
        for (int n = 0; n < 4; ++n)
          acc[m][n] = __builtin_amdgcn_mfma_f32_16x16x32_bf16(afr[m], bfr[n], acc[m][n], 0, 0, 0);
    }
  }

#pragma unroll
  for (int m = 0; m < 4; ++m)
#pragma unroll
    for (int n = 0; n < 4; ++n) {
      const int col = bn + wc + n * 16 + l15;
      if (GUARD_NST && col >= N) continue;
      const float bv = bias[col];
#pragma unroll
      for (int r = 0; r < 4; ++r) {
        const int row = bm + wr + m * 16 + l4 * 4 + r;
        C[(size_t)row * N + col] = acc[m][n][r] + bv;
      }
    }
}

// LIF scan, fp32 currents -> bf16 spikes (exact 0/1)
__global__ __launch_bounds__(256)
void lif_scan_bf(const float* __restrict__ cur, unsigned short* __restrict__ spk,
                 int NE, int nt) {
  const int tid = blockIdx.x * 256 + threadIdx.x;
  float mem = 0.0f;
  for (int t = 0; t < nt; ++t) {
    const float c = cur[(size_t)t * NE + tid];
    const float reset = (mem > 1.0f) ? 1.0f : 0.0f;
    mem = __fsub_rn(__fadd_rn(__fmul_rn(0.9f, mem), c), reset);
    spk[(size_t)t * NE + tid] = (mem > 1.0f) ? (unsigned short)0x3F80 : (unsigned short)0;
  }
}

// LIF scan, fp32 in-place (cur and spk alias)
__global__ __launch_bounds__(256)
void lif_scan_f32(const float* cur, float* spk, int NE, int nt) {
  const int tid = blockIdx.x * 256 + threadIdx.x;
  float mem = 0.0f;
  for (int t = 0; t < nt; ++t) {
    const float c = cur[(size_t)t * NE + tid];
    const float reset = (mem > 1.0f) ? 1.0f : 0.0f;
    mem = __fsub_rn(__fadd_rn(__fmul_rn(0.9f, mem), c), reset);
    spk[(size_t)t * NE + tid] = (mem > 1.0f) ? 1.0f : 0.0f;
  }
}

extern "C" void kernel_launch(void* const* d_in, const int* in_sizes, int n_in,
                              void* d_out, int out_size, void* d_ws, size_t ws_size,
                              hipStream_t stream) {
  const float* x  = (const float*)d_in[0];  // [T,B,D]
  const float* W1 = (const float*)d_in[1];  // [H,D]
  const float* b1 = (const float*)d_in[2];  // [H]
  const float* W2 = (const float*)d_in[3];  // [D,H]
  const float* b2 = (const float*)d_in[4];  // [D]
  float* out = (float*)d_out;               // [T,B,D]

  const size_t w1s_elems = (size_t)3 * HH * K1PAD;     // 3*256*800
  const size_t w2s_elems = (size_t)3 * N2PAD * HH;     // 3*896*256
  unsigned short* W1s = (unsigned short*)d_ws;
  unsigned short* W2s = W1s + w1s_elems;
  float* cur1 = (float*)(W2s + w2s_elems);
  unsigned short* spk1 = (unsigned short*)(cur1 + (size_t)MM * HH);

  dim3 blk(256);

  split_w<<<dim3((HH * K1PAD + 255) / 256), blk, 0, stream>>>(W1, W1s, HH, DD, HH, K1PAD);
  split_w<<<dim3((N2PAD * HH + 255) / 256), blk, 0, stream>>>(W2, W2s, DD, HH, N2PAD, HH);

  // layer 1: cur1[M,256] = X[M,784] @ W1^T + b1  (A fp32, reg-staged convert)
  gemm_mfma<true, true, false><<<dim3(MM / 128, HH / 128), blk, 0, stream>>>(
      x, W1s, (size_t)HH * K1PAD, b1, cur1, MM, HH, DD, K1PAD);

  lif_scan_bf<<<dim3((BB * HH) / 256), blk, 0, stream>>>(cur1, spk1, BB * HH, TT);

  // layer 2: out[M,784] = spk1[M,256] @ W2^T + b2  (A bf16 glds, B rows padded to 896)
  gemm_mfma<false, false, true><<<dim3(MM / 128, N2PAD / 128), blk, 0, stream>>>(
      spk1, W2s, (size_t)N2PAD * HH, b2, out, MM, DD, HH, HH);

  lif_scan_f32<<<dim3((BB * DD) / 256), blk, 0, stream>>>(out, out, BB * DD, TT);
}

// Round 4
// 148.403 us; speedup vs baseline: 2.3750x; 1.0885x over previous
//
#include <hip/hip_runtime.h>

typedef __attribute__((ext_vector_type(8))) short bf16x8;
typedef __attribute__((ext_vector_type(4))) float f32x4;

static constexpr int TT = 100, BB = 256, DD = 784, HH = 256;
static constexpr int MM = TT * BB;      // 25600
static constexpr int K1PAD = 800;       // 784 -> 25*32
static constexpr int N2PAD = 896;       // 784 -> 7*128

__device__ __forceinline__ unsigned short f2bf(float x) {
  unsigned u = __float_as_uint(x);
  return (unsigned short)((u + 0x7FFFu + ((u >> 16) & 1u)) >> 16);
}
__device__ __forceinline__ float bf2f(unsigned short h) {
  return __uint_as_float(((unsigned)h) << 16);
}
__device__ __forceinline__ void glds16(const void* g, void* l) {
  __builtin_amdgcn_global_load_lds(
      (const __attribute__((address_space(1))) unsigned int*)g,
      (__attribute__((address_space(3))) unsigned int*)l, 16, 0, 0);
}

// Split fp32 W[N][K] into 3 bf16 planes [Npad][Kpad] (w = p0+p1+p2, err <= 2^-27|w|).
__global__ __launch_bounds__(256)
void split_w(const float* __restrict__ W, unsigned short* __restrict__ Ws,
             int N, int K, int Npad, int Kpad) {
  int idx = blockIdx.x * 256 + threadIdx.x;
  int total = Npad * Kpad;
  if (idx >= total) return;
  int row = idx / Kpad, col = idx - row * Kpad;
  float w = (row < N && col < K) ? W[row * K + col] : 0.0f;
  unsigned short h0 = f2bf(w);
  float r1 = w - bf2f(h0);
  unsigned short h1 = f2bf(r1);
  float r2 = r1 - bf2f(h1);
  Ws[idx] = h0;
  Ws[total + idx] = h1;
  Ws[2 * total + idx] = f2bf(r2);
}

// C[M,N] = A[M,K] @ (sum of 3 bf16 planes of B)^T + bias[N]
// BM=BN=128, BK=32, 4 waves 2x2 (64x64), mfma_f32_16x16x32_bf16.
// Double-buffered LDS, ONE barrier per K-step. LDS layout XOR-swizzled:
//   phys_chunk(row, log_chunk) = log_chunk ^ (((row & 15) >> 1) & 3)   [16B chunks]
// glds keeps a LINEAR dest; the swizzle is applied by permuting each lane's
// GLOBAL source chunk (rule: linear dest + inverse-swizzled source + swizzled read).
template<bool CONV_A, bool GUARD_KA, bool GUARD_NST>
__global__ __launch_bounds__(256, 2)
void gemm_mfma(const void* __restrict__ Aptr, const unsigned short* __restrict__ Bs,
               size_t planeStride, const float* __restrict__ bias,
               float* __restrict__ C, int M, int N, int K, int Kpad) {
  __shared__ unsigned short Asm[2][128 * 32];      // 16 KB
  __shared__ unsigned short Bsm[2][3][128 * 32];   // 48 KB
  const int tid = threadIdx.x;
  const int bm = blockIdx.x * 128, bn = blockIdx.y * 128;
  const int wid = tid >> 6, lane = tid & 63;
  const int wr = (wid >> 1) * 64, wc = (wid & 1) * 64;
  const int l15 = lane & 15, l4 = lane >> 4;

  f32x4 acc[4][4];
#pragma unroll
  for (int m = 0; m < 4; ++m)
#pragma unroll
    for (int n = 0; n < 4; ++n) acc[m][n] = (f32x4){0.f, 0.f, 0.f, 0.f};

  // glds source: lane fills phys row (lane>>2), phys chunk (lane&3) of a 16-row
  // stripe; content must be logical chunk (lane&3) ^ ((lane>>3)&3).
  const int rl = wid * 32 + (lane >> 2);
  const int ce = (((lane & 3) ^ ((lane >> 3) & 3)) * 8);

  const unsigned short* bsrc[3][2];
#pragma unroll
  for (int s = 0; s < 3; ++s)
#pragma unroll
    for (int i = 0; i < 2; ++i)
      bsrc[s][i] = Bs + (size_t)s * planeStride + (size_t)(bn + rl + i * 16) * Kpad + ce;

  const unsigned short* asrc[2];
  if (!CONV_A) {
    const unsigned short* Ab = (const unsigned short*)Aptr;
#pragma unroll
    for (int i = 0; i < 2; ++i)
      asrc[i] = Ab + (size_t)(bm + rl + i * 16) * Kpad + ce;
  }

  // fragment reads: row = base + l15, logical chunk = l4 -> phys chunk swizzled
  const int rdsw = (l4 ^ ((l15 >> 1) & 3)) * 8;

  // CONV_A reg-staging: thread covers rows tid>>2 and +64; source logical chunk
  // tid&3, LDS dest phys chunk (tid&3)^((tid>>3)&3).
  const int r0 = tid >> 2;
  const int c0log = (tid & 3) * 8;
  const int c0phys = ((tid & 3) ^ ((tid >> 3) & 3)) * 8;
  const float* Af = (const float*)Aptr;
  uint4 a_st[2];

  auto loadA = [&](int kb) {
    const int col = kb * 32 + c0log;
#pragma unroll
    for (int i = 0; i < 2; ++i) {
      const int row = bm + r0 + i * 64;
      float4 f0 = make_float4(0.f, 0.f, 0.f, 0.f), f1 = f0;
      if (!GUARD_KA || col < K) {      // K % 8 == 0: whole octet in/out
        f0 = *(const float4*)&Af[(size_t)row * K + col];
        f1 = *(const float4*)&Af[(size_t)row * K + col + 4];
      }
      uint4 v;
      v.x = (unsigned)f2bf(f0.x) | ((unsigned)f2bf(f0.y) << 16);
      v.y = (unsigned)f2bf(f0.z) | ((unsigned)f2bf(f0.w) << 16);
      v.z = (unsigned)f2bf(f1.x) | ((unsigned)f2bf(f1.y) << 16);
      v.w = (unsigned)f2bf(f1.z) | ((unsigned)f2bf(f1.w) << 16);
      a_st[i] = v;
    }
  };

  const int nkb = Kpad / 32;

  // ---- prologue: stage buffer 0 (tile 0), prefetch A regs for tile 1 ----
  if (CONV_A) loadA(0);
  else {
    glds16(asrc[0], &Asm[0][(wid * 32) * 32]);
    glds16(asrc[1], &Asm[0][(wid * 32 + 16) * 32]);
  }
#pragma unroll
  for (int s = 0; s < 3; ++s) {
    glds16(bsrc[s][0], &Bsm[0][s][(wid * 32) * 32]);
    glds16(bsrc[s][1], &Bsm[0][s][(wid * 32 + 16) * 32]);
  }
  if (CONV_A) {
    *(uint4*)&Asm[0][r0 * 32 + c0phys] = a_st[0];
    *(uint4*)&Asm[0][(r0 + 64) * 32 + c0phys] = a_st[1];
    if (nkb > 1) loadA(1);
  }

  for (int kb = 0; kb < nkb; ++kb) {
    const int cur = kb & 1, nxt = cur ^ 1;
    __syncthreads();   // buf[cur] staged (vmcnt+lgkm drained); buf[nxt] free to overwrite

    if (kb + 1 < nkb) {
      const int k0n = (kb + 1) * 32;
#pragma unroll
      for (int s = 0; s < 3; ++s) {
        glds16(bsrc[s][0] + k0n, &Bsm[nxt][s][(wid * 32) * 32]);
        glds16(bsrc[s][1] + k0n, &Bsm[nxt][s][(wid * 32 + 16) * 32]);
      }
      if (CONV_A) {
        *(uint4*)&Asm[nxt][r0 * 32 + c0phys] = a_st[0];
        *(uint4*)&Asm[nxt][(r0 + 64) * 32 + c0phys] = a_st[1];
        if (kb + 2 < nkb) loadA(kb + 2);
      } else {
        glds16(asrc[0] + k0n, &Asm[nxt][(wid * 32) * 32]);
        glds16(asrc[1] + k0n, &Asm[nxt][(wid * 32 + 16) * 32]);
      }
    }

    bf16x8 afr[4];
#pragma unroll
    for (int m = 0; m < 4; ++m)
      afr[m] = *(const bf16x8*)&Asm[cur][(wr + m * 16 + l15) * 32 + rdsw];
#pragma unroll
    for (int s = 0; s < 3; ++s) {
      bf16x8 bfr[4];
#pragma unroll
      for (int n = 0; n < 4; ++n)
        bfr[n] = *(const bf16x8*)&Bsm[cur][s][(wc + n * 16 + l15) * 32 + rdsw];
#pragma unroll
      for (int m = 0; m < 4; ++m)
#pragma unroll
        for (int n = 0; n < 4; ++n)
          acc[m][n] = __builtin_amdgcn_mfma_f32_16x16x32_bf16(afr[m], bfr[n], acc[m][n], 0, 0, 0);
    }
  }

#pragma unroll
  for (int m = 0; m < 4; ++m)
#pragma unroll
    for (int n = 0; n < 4; ++n) {
      const int col = bn + wc + n * 16 + l15;
      if (GUARD_NST && col >= N) continue;
      const float bv = bias[col];
#pragma unroll
      for (int r = 0; r < 4; ++r) {
        const int row = bm + wr + m * 16 + l4 * 4 + r;
        C[(size_t)row * N + col] = acc[m][n][r] + bv;
      }
    }
}

__device__ __forceinline__ float lif_step(float& mem, float c) {
  const float reset = (mem > 1.0f) ? 1.0f : 0.0f;
  mem = __fsub_rn(__fadd_rn(__fmul_rn(0.9f, mem), c), reset);
  return (mem > 1.0f) ? 1.0f : 0.0f;
}

// fp32 currents -> bf16 spikes, 4 elems/thread
__global__ __launch_bounds__(256)
void lif_scan_bf4(const float4* __restrict__ cur, uint2* __restrict__ spk,
                  int NE4, int nt) {
  const int tid = blockIdx.x * 256 + threadIdx.x;
  float4 mem = make_float4(0.f, 0.f, 0.f, 0.f);
#pragma unroll 4
  for (int t = 0; t < nt; ++t) {
    const float4 c = cur[(size_t)t * NE4 + tid];
    unsigned s0 = lif_step(mem.x, c.x) != 0.f ? 0x3F80u : 0u;
    unsigned s1 = lif_step(mem.y, c.y) != 0.f ? 0x3F80u : 0u;
    unsigned s2 = lif_step(mem.z, c.z) != 0.f ? 0x3F80u : 0u;
    unsigned s3 = lif_step(mem.w, c.w) != 0.f ? 0x3F80u : 0u;
    uint2 o;
    o.x = s0 | (s1 << 16);
    o.y = s2 | (s3 << 16);
    spk[(size_t)t * NE4 + tid] = o;
  }
}

// fp32 in-place, 4 elems/thread
__global__ __launch_bounds__(256)
void lif_scan_f32x4(float4* buf, int NE4, int nt) {
  const int tid = blockIdx.x * 256 + threadIdx.x;
  float4 mem = make_float4(0.f, 0.f, 0.f, 0.f);
#pragma unroll 4
  for (int t = 0; t < nt; ++t) {
    const float4 c = buf[(size_t)t * NE4 + tid];
    float4 o;
    o.x = lif_step(mem.x, c.x);
    o.y = lif_step(mem.y, c.y);
    o.z = lif_step(mem.z, c.z);
    o.w = lif_step(mem.w, c.w);
    buf[(size_t)t * NE4 + tid] = o;
  }
}

extern "C" void kernel_launch(void* const* d_in, const int* in_sizes, int n_in,
                              void* d_out, int out_size, void* d_ws, size_t ws_size,
                              hipStream_t stream) {
  const float* x  = (const float*)d_in[0];
  const float* W1 = (const float*)d_in[1];
  const float* b1 = (const float*)d_in[2];
  const float* W2 = (const float*)d_in[3];
  const float* b2 = (const float*)d_in[4];
  float* out = (float*)d_out;

  const size_t w1s_elems = (size_t)3 * HH * K1PAD;
  const size_t w2s_elems = (size_t)3 * N2PAD * HH;
  unsigned short* W1s = (unsigned short*)d_ws;
  unsigned short* W2s = W1s + w1s_elems;
  float* cur1 = (float*)(W2s + w2s_elems);
  unsigned short* spk1 = (unsigned short*)(cur1 + (size_t)MM * HH);

  dim3 blk(256);

  split_w<<<dim3((HH * K1PAD + 255) / 256), blk, 0, stream>>>(W1, W1s, HH, DD, HH, K1PAD);
  split_w<<<dim3((N2PAD * HH + 255) / 256), blk, 0, stream>>>(W2, W2s, DD, HH, N2PAD, HH);

  // layer 1: cur1[M,256] = X[M,784] @ W1^T + b1  (A fp32, reg-staged convert)
  gemm_mfma<true, true, false><<<dim3(MM / 128, HH / 128), blk, 0, stream>>>(
      x, W1s, (size_t)HH * K1PAD, b1, cur1, MM, HH, DD, K1PAD);

  lif_scan_bf4<<<dim3((BB * HH / 4) / 256), blk, 0, stream>>>(
      (const float4*)cur1, (uint2*)spk1, BB * HH / 4, TT);

  // layer 2: out[M,784] = spk1[M,256] @ W2^T + b2  (A bf16 via glds)
  gemm_mfma<false, false, true><<<dim3(MM / 128, N2PAD / 128), blk, 0, stream>>>(
      spk1, W2s, (size_t)N2PAD * HH, b2, out, MM, DD, HH, HH);

  lif_scan_f32x4<<<dim3((BB * DD / 4) / 256), blk, 0, stream>>>(
      (float4*)out, BB * DD / 4, TT);
}

// Round 5
// 141.638 us; speedup vs baseline: 2.4885x; 1.0478x over previous
//
#include <hip/hip_runtime.h>

typedef __attribute__((ext_vector_type(8))) _Float16 f16x8;
typedef __attribute__((ext_vector_type(4))) float f32x4;

static constexpr int TT = 100, BB = 256, DD = 784, HH = 256;
static constexpr int MM = TT * BB;      // 25600
static constexpr int K1PAD = 800;       // 784 -> 25*32
static constexpr int N2PAD = 896;       // 784 -> 7*128
static constexpr float MIDSC = 2048.0f, INVMID = 1.0f / 2048.0f;

__device__ __forceinline__ unsigned short f2h(float x) {
  _Float16 h = (_Float16)x;
  return *(unsigned short*)&h;
}
__device__ __forceinline__ float h2f(unsigned short u) {
  _Float16 h = *(_Float16*)&u;
  return (float)h;
}
__device__ __forceinline__ void glds16(const void* g, void* l) {
  __builtin_amdgcn_global_load_lds(
      (const __attribute__((address_space(1))) unsigned int*)g,
      (__attribute__((address_space(3))) unsigned int*)l, 16, 0, 0);
}

// Split fp32 W[N][K] into 2 f16 planes [Npad][Kpad]:
//   p0 = f16(w),  p1 = f16((w - p0) * 2048)
// Reconstruction p0 + p1/2048 matches w to ~2^-22 relative (subnormal tails ~3e-8 abs).
__global__ __launch_bounds__(256)
void split_w(const float* __restrict__ W, unsigned short* __restrict__ Ws,
             int N, int K, int Npad, int Kpad) {
  int idx = blockIdx.x * 256 + threadIdx.x;
  int total = Npad * Kpad;
  if (idx >= total) return;
  int row = idx / Kpad, col = idx - row * Kpad;
  float w = (row < N && col < K) ? W[row * K + col] : 0.0f;
  unsigned short h0 = f2h(w);
  float r = (w - h2f(h0)) * MIDSC;    // exact subtract, exact pow2 scale
  Ws[idx] = h0;
  Ws[total + idx] = f2h(r);
}

// C[M,N] = A[M,K] @ (p0 + p1/2048 of B)^T + bias[N]
// BM=BN=128, BK=32, 4 waves 2x2 (64x64), mfma_f32_16x16x32_f16, dual accumulators.
// Double-buffered LDS, ONE barrier per K-step. XOR-swizzled LDS (16B chunks):
//   phys_chunk(row, log_chunk) = log_chunk ^ (((row & 15) >> 1) & 3)
// glds keeps a LINEAR dest; swizzle applied by permuting each lane's GLOBAL source chunk.
template<bool CONV_A, bool GUARD_KA, bool GUARD_NST>
__global__ __launch_bounds__(256, 2)
void gemm_mfma(const void* __restrict__ Aptr, const unsigned short* __restrict__ Bs,
               size_t planeStride, const float* __restrict__ bias,
               float* __restrict__ C, int M, int N, int K, int Kpad) {
  __shared__ unsigned short Asm[2][128 * 32];      // 16 KB
  __shared__ unsigned short Bsm[2][2][128 * 32];   // 32 KB
  const int tid = threadIdx.x;
  const int bm = blockIdx.x * 128, bn = blockIdx.y * 128;
  const int wid = tid >> 6, lane = tid & 63;
  const int wr = (wid >> 1) * 64, wc = (wid & 1) * 64;
  const int l15 = lane & 15, l4 = lane >> 4;

  f32x4 acc[2][4][4];
#pragma unroll
  for (int s = 0; s < 2; ++s)
#pragma unroll
    for (int m = 0; m < 4; ++m)
#pragma unroll
      for (int n = 0; n < 4; ++n) acc[s][m][n] = (f32x4){0.f, 0.f, 0.f, 0.f};

  // glds source: lane fills phys row (lane>>2), phys chunk (lane&3) of a 16-row
  // stripe; content must be logical chunk (lane&3) ^ ((lane>>3)&3).
  const int rl = wid * 32 + (lane >> 2);
  const int ce = (((lane & 3) ^ ((lane >> 3) & 3)) * 8);

  const unsigned short* bsrc[2][2];
#pragma unroll
  for (int s = 0; s < 2; ++s)
#pragma unroll
    for (int i = 0; i < 2; ++i)
      bsrc[s][i] = Bs + (size_t)s * planeStride + (size_t)(bn + rl + i * 16) * Kpad + ce;

  const unsigned short* asrc[2];
  if (!CONV_A) {
    const unsigned short* Ab = (const unsigned short*)Aptr;
#pragma unroll
    for (int i = 0; i < 2; ++i)
      asrc[i] = Ab + (size_t)(bm + rl + i * 16) * Kpad + ce;
  }

  // fragment reads: row = base + l15, logical chunk = l4 -> phys chunk swizzled
  const int rdsw = (l4 ^ ((l15 >> 1) & 3)) * 8;

  // CONV_A reg-staging: thread covers rows tid>>2 and +64; source logical chunk
  // tid&3, LDS dest phys chunk (tid&3)^((tid>>3)&3). A is BINARY -> select f16 one.
  const int r0 = tid >> 2;
  const int c0log = (tid & 3) * 8;
  const int c0phys = ((tid & 3) ^ ((tid >> 3) & 3)) * 8;
  const float* Af = (const float*)Aptr;
  uint4 a_st[2];

  auto loadA = [&](int kb) {
    const int col = kb * 32 + c0log;
#pragma unroll
    for (int i = 0; i < 2; ++i) {
      const int row = bm + r0 + i * 64;
      float4 f0 = make_float4(0.f, 0.f, 0.f, 0.f), f1 = f0;
      if (!GUARD_KA || col < K) {      // K % 8 == 0: whole octet in/out
        f0 = *(const float4*)&Af[(size_t)row * K + col];
        f1 = *(const float4*)&Af[(size_t)row * K + col + 4];
      }
      const unsigned ONE = 0x3C00u;    // f16 1.0
      uint4 v;
      v.x = (f0.x != 0.f ? ONE : 0u) | (f0.y != 0.f ? ONE << 16 : 0u);
      v.y = (f0.z != 0.f ? ONE : 0u) | (f0.w != 0.f ? ONE << 16 : 0u);
      v.z = (f1.x != 0.f ? ONE : 0u) | (f1.y != 0.f ? ONE << 16 : 0u);
      v.w = (f1.z != 0.f ? ONE : 0u) | (f1.w != 0.f ? ONE << 16 : 0u);
      a_st[i] = v;
    }
  };

  const int nkb = Kpad / 32;

  // ---- prologue: stage buffer 0 (tile 0), prefetch A regs for tile 1 ----
  if (CONV_A) loadA(0);
  else {
    glds16(asrc[0], &Asm[0][(wid * 32) * 32]);
    glds16(asrc[1], &Asm[0][(wid * 32 + 16) * 32]);
  }
#pragma unroll
  for (int s = 0; s < 2; ++s) {
    glds16(bsrc[s][0], &Bsm[0][s][(wid * 32) * 32]);
    glds16(bsrc[s][1], &Bsm[0][s][(wid * 32 + 16) * 32]);
  }
  if (CONV_A) {
    *(uint4*)&Asm[0][r0 * 32 + c0phys] = a_st[0];
    *(uint4*)&Asm[0][(r0 + 64) * 32 + c0phys] = a_st[1];
    if (nkb > 1) loadA(1);
  }

  for (int kb = 0; kb < nkb; ++kb) {
    const int cur = kb & 1, nxt = cur ^ 1;
    __syncthreads();   // buf[cur] staged (vmcnt+lgkm drained); buf[nxt] free

    if (kb + 1 < nkb) {
      const int k0n = (kb + 1) * 32;
#pragma unroll
      for (int s = 0; s < 2; ++s) {
        glds16(bsrc[s][0] + k0n, &Bsm[nxt][s][(wid * 32) * 32]);
        glds16(bsrc[s][1] + k0n, &Bsm[nxt][s][(wid * 32 + 16) * 32]);
      }
      if (CONV_A) {
        *(uint4*)&Asm[nxt][r0 * 32 + c0phys] = a_st[0];
        *(uint4*)&Asm[nxt][(r0 + 64) * 32 + c0phys] = a_st[1];
        if (kb + 2 < nkb) loadA(kb + 2);
      } else {
        glds16(asrc[0] + k0n, &Asm[nxt][(wid * 32) * 32]);
        glds16(asrc[1] + k0n, &Asm[nxt][(wid * 32 + 16) * 32]);
      }
    }

    f16x8 afr[4];
#pragma unroll
    for (int m = 0; m < 4; ++m)
      afr[m] = *(const f16x8*)&Asm[cur][(wr + m * 16 + l15) * 32 + rdsw];
#pragma unroll
    for (int s = 0; s < 2; ++s) {
      f16x8 bfr[4];
#pragma unroll
      for (int n = 0; n < 4; ++n)
        bfr[n] = *(const f16x8*)&Bsm[cur][s][(wc + n * 16 + l15) * 32 + rdsw];
#pragma unroll
      for (int m = 0; m < 4; ++m)
#pragma unroll
        for (int n = 0; n < 4; ++n)
          acc[s][m][n] = __builtin_amdgcn_mfma_f32_16x16x32_f16(afr[m], bfr[n], acc[s][m][n], 0, 0, 0);
    }
  }

#pragma unroll
  for (int m = 0; m < 4; ++m)
#pragma unroll
    for (int n = 0; n < 4; ++n) {
      const int col = bn + wc + n * 16 + l15;
      if (GUARD_NST && col >= N) continue;
      const float bv = bias[col];
#pragma unroll
      for (int r = 0; r < 4; ++r) {
        const int row = bm + wr + m * 16 + l4 * 4 + r;
        C[(size_t)row * N + col] = fmaf(acc[1][m][n][r], INVMID, acc[0][m][n][r]) + bv;
      }
    }
}

__device__ __forceinline__ float lif_step(float& mem, float c) {
  const float reset = (mem > 1.0f) ? 1.0f : 0.0f;
  mem = __fsub_rn(__fadd_rn(__fmul_rn(0.9f, mem), c), reset);
  return (mem > 1.0f) ? 1.0f : 0.0f;
}

// fp32 currents -> f16 spikes, 4 elems/thread
__global__ __launch_bounds__(256)
void lif_scan_h4(const float4* __restrict__ cur, uint2* __restrict__ spk,
                 int NE4, int nt) {
  const int tid = blockIdx.x * 256 + threadIdx.x;
  float4 mem = make_float4(0.f, 0.f, 0.f, 0.f);
#pragma unroll 4
  for (int t = 0; t < nt; ++t) {
    const float4 c = cur[(size_t)t * NE4 + tid];
    unsigned s0 = lif_step(mem.x, c.x) != 0.f ? 0x3C00u : 0u;
    unsigned s1 = lif_step(mem.y, c.y) != 0.f ? 0x3C00u : 0u;
    unsigned s2 = lif_step(mem.z, c.z) != 0.f ? 0x3C00u : 0u;
    unsigned s3 = lif_step(mem.w, c.w) != 0.f ? 0x3C00u : 0u;
    uint2 o;
    o.x = s0 | (s1 << 16);
    o.y = s2 | (s3 << 16);
    spk[(size_t)t * NE4 + tid] = o;
  }
}

// fp32 in-place, 4 elems/thread
__global__ __launch_bounds__(256)
void lif_scan_f32x4(float4* buf, int NE4, int nt) {
  const int tid = blockIdx.x * 256 + threadIdx.x;
  float4 mem = make_float4(0.f, 0.f, 0.f, 0.f);
#pragma unroll 4
  for (int t = 0; t < nt; ++t) {
    const float4 c = buf[(size_t)t * NE4 + tid];
    float4 o;
    o.x = lif_step(mem.x, c.x);
    o.y = lif_step(mem.y, c.y);
    o.z = lif_step(mem.z, c.z);
    o.w = lif_step(mem.w, c.w);
    buf[(size_t)t * NE4 + tid] = o;
  }
}

extern "C" void kernel_launch(void* const* d_in, const int* in_sizes, int n_in,
                              void* d_out, int out_size, void* d_ws, size_t ws_size,
                              hipStream_t stream) {
  const float* x  = (const float*)d_in[0];
  const float* W1 = (const float*)d_in[1];
  const float* b1 = (const float*)d_in[2];
  const float* W2 = (const float*)d_in[3];
  const float* b2 = (const float*)d_in[4];
  float* out = (float*)d_out;

  const size_t w1s_elems = (size_t)2 * HH * K1PAD;
  const size_t w2s_elems = (size_t)2 * N2PAD * HH;
  unsigned short* W1s = (unsigned short*)d_ws;
  unsigned short* W2s = W1s + w1s_elems;
  float* cur1 = (float*)(W2s + w2s_elems);
  unsigned short* spk1 = (unsigned short*)(cur1 + (size_t)MM * HH);

  dim3 blk(256);

  split_w<<<dim3((HH * K1PAD + 255) / 256), blk, 0, stream>>>(W1, W1s, HH, DD, HH, K1PAD);
  split_w<<<dim3((N2PAD * HH + 255) / 256), blk, 0, stream>>>(W2, W2s, DD, HH, N2PAD, HH);

  // layer 1: cur1[M,256] = X[M,784] @ W1^T + b1  (A fp32 binary, reg-staged select)
  gemm_mfma<true, true, false><<<dim3(MM / 128, HH / 128), blk, 0, stream>>>(
      x, W1s, (size_t)HH * K1PAD, b1, cur1, MM, HH, DD, K1PAD);

  lif_scan_h4<<<dim3((BB * HH / 4) / 256), blk, 0, stream>>>(
      (const float4*)cur1, (uint2*)spk1, BB * HH / 4, TT);

  // layer 2: out[M,784] = spk1[M,256] @ W2^T + b2  (A f16 via glds)
  gemm_mfma<false, false, true><<<dim3(MM / 128, N2PAD / 128), blk, 0, stream>>>(
      spk1, W2s, (size_t)N2PAD * HH, b2, out, MM, DD, HH, HH);

  lif_scan_f32x4<<<dim3((BB * DD / 4) / 256), blk, 0, stream>>>(
      (float4*)out, BB * DD / 4, TT);
}